// Round 1
// baseline (149.415 us; speedup 1.0000x reference)
//
#include <hip/hip_runtime.h>
#include <hip/hip_bf16.h>
#include <stdint.h>

// Problem constants
#define MB 8192     // batch (rows and cols of sim)
#define KD 256      // embedding dim
#define BM 64       // rows per block
#define BN 64       // cols per chunk
#define NSPLIT 8    // column slabs
#define SLAB (MB / NSPLIT)   // 1024 cols per slab

typedef __attribute__((ext_vector_type(8))) short bf16x8;
typedef __attribute__((ext_vector_type(4))) float f32x4;

__device__ __forceinline__ unsigned short f2bf(float x) {
  union { float f; uint32_t u; } v; v.f = x;
  uint32_t r = v.u + 0x7fffu + ((v.u >> 16) & 1u);   // RNE
  return (unsigned short)(r >> 16);
}

// ---------------- prep: fp32 -> bf16 for A and B, plus logq ----------------
__global__ __launch_bounds__(256) void convert_kernel(
    const float* __restrict__ A, const float* __restrict__ B,
    const float* __restrict__ q,
    unsigned short* __restrict__ Abf, unsigned short* __restrict__ Bbf,
    float* __restrict__ logq) {
  int t = blockIdx.x * 256 + threadIdx.x;        // 524288 threads, 1 float4 each
  const float4 a = ((const float4*)A)[t];
  const float4 b = ((const float4*)B)[t];
  ushort4 oa, ob;
  oa.x = f2bf(a.x); oa.y = f2bf(a.y); oa.z = f2bf(a.z); oa.w = f2bf(a.w);
  ob.x = f2bf(b.x); ob.y = f2bf(b.y); ob.z = f2bf(b.z); ob.w = f2bf(b.w);
  ((ushort4*)Abf)[t] = oa;
  ((ushort4*)Bbf)[t] = ob;
  if (t < MB) logq[t] = logf(q[t]);
}

// ---------------- pos_sim in fp32 (wave per row) ----------------
__global__ __launch_bounds__(256) void possim_kernel(
    const float* __restrict__ A, const float* __restrict__ T,
    float* __restrict__ pos) {
  int gw = (blockIdx.x * 256 + threadIdx.x) >> 6;   // wave id == row
  int lane = threadIdx.x & 63;
  const float4 a = *(const float4*)(A + gw * KD + lane * 4);
  const float4 t = *(const float4*)(T + gw * KD + lane * 4);
  float d = a.x * t.x + a.y * t.y + a.z * t.z + a.w * t.w;
  #pragma unroll
  for (int off = 32; off; off >>= 1) d += __shfl_down(d, off, 64);
  if (lane == 0) pos[gw] = d;
}

// ---------------- fused GEMM + masked online logsumexp ----------------
__global__ __launch_bounds__(256) void fused_kernel(
    const unsigned short* __restrict__ Abf,
    const unsigned short* __restrict__ Bbf,
    const int* __restrict__ ids,
    const float* __restrict__ logq,
    float* __restrict__ pm, float* __restrict__ ps, float* __restrict__ pc) {
  const int rowbase = blockIdx.x * BM;
  const int slab = blockIdx.y;
  const int colbase0 = slab * SLAB;
  const int tid = threadIdx.x;
  const int wave = tid >> 6;
  const int lane = tid & 63;
  const int quad = lane >> 4;
  const int lpos = lane & 15;

  __shared__ unsigned short Bs[BN][KD + 8];   // +8 pad: 2-way-only bank aliasing

  // A fragments resident: wave owns rows [rowbase + wave*16, +16)
  const int arow = rowbase + wave * 16 + lpos;      // A-frag: m = lane&15
  bf16x8 afrag[8];
  #pragma unroll
  for (int kb = 0; kb < 8; ++kb)
    afrag[kb] = *(const bf16x8*)(Abf + arow * KD + kb * 32 + quad * 8);

  // per-lane row state: reg r -> row rowbase + wave*16 + quad*4 + r
  float mrun[4], srun[4], crun[4];
  int ids_row[4];
  #pragma unroll
  for (int r = 0; r < 4; ++r) {
    mrun[r] = -1e30f; srun[r] = 0.0f; crun[r] = 0.0f;
    ids_row[r] = ids[rowbase + wave * 16 + quad * 4 + r];
  }

  for (int ch = 0; ch < SLAB / BN; ++ch) {
    const int colchunk = colbase0 + ch * BN;
    __syncthreads();                           // protect Bs from overwrite
    // stage B chunk (64 cols x 256 k): 2048 x 16B segments, 8 per thread
    #pragma unroll
    for (int s = 0; s < 8; ++s) {
      int seg = tid + s * 256;
      int n = seg >> 5;
      int k16 = seg & 31;
      uint4 v = *(const uint4*)(Bbf + (colchunk + n) * KD + k16 * 8);
      *(uint4*)(&Bs[n][k16 * 8]) = v;
    }
    __syncthreads();

    #pragma unroll
    for (int ct = 0; ct < 4; ++ct) {
      const int bn = ct * 16 + lpos;           // B-frag: n = lane&15
      bf16x8 bfrag[8];
      #pragma unroll
      for (int kb = 0; kb < 8; ++kb)
        bfrag[kb] = *(const bf16x8*)(&Bs[bn][kb * 32 + quad * 8]);
      f32x4 acc = {0.0f, 0.0f, 0.0f, 0.0f};
      #pragma unroll
      for (int kb = 0; kb < 8; ++kb)
        acc = __builtin_amdgcn_mfma_f32_16x16x32_bf16(afrag[kb], bfrag[kb], acc, 0, 0, 0);
      // epilogue: lane holds sim[quad*4+r][lpos] of this tile
      const int j = colchunk + ct * 16 + lpos;
      const int idj = ids[j];
      const float lqj = logq[j];
      #pragma unroll
      for (int r = 0; r < 4; ++r) {
        const bool valid = (idj != ids_row[r]);
        const float y = valid ? (acc[r] - lqj) : -1e30f;
        const float mn = fmaxf(mrun[r], y);
        srun[r] = srun[r] * __expf(mrun[r] - mn) + (valid ? __expf(y - mn) : 0.0f);
        mrun[r] = mn;
        crun[r] += valid ? 1.0f : 0.0f;
      }
    }
  }

  // reduce (m,s,c) across the 16 lanes of each quad (cols of the row)
  #pragma unroll
  for (int r = 0; r < 4; ++r) {
    float m = mrun[r], s = srun[r], c = crun[r];
    #pragma unroll
    for (int off = 1; off < 16; off <<= 1) {
      float mo = __shfl_xor(m, off, 64);
      float so = __shfl_xor(s, off, 64);
      float co = __shfl_xor(c, off, 64);
      float mn = fmaxf(m, mo);
      s = s * __expf(m - mn) + so * __expf(mo - mn);
      m = mn;
      c += co;
    }
    if (lpos == 0) {
      int gi = rowbase + wave * 16 + quad * 4 + r;
      pm[slab * MB + gi] = m;
      ps[slab * MB + gi] = s;
      pc[slab * MB + gi] = c;
    }
  }
}

// ---------------- finalize: merge slabs, per-row loss, mean ----------------
__global__ __launch_bounds__(256) void finalize_kernel(
    const float* __restrict__ pm, const float* __restrict__ ps,
    const float* __restrict__ pc, const float* __restrict__ pos,
    const float* __restrict__ q, float* __restrict__ out) {
  int i = blockIdx.x * 256 + threadIdx.x;   // 32 blocks -> 8192 threads
  float m = -1e30f, s = 0.0f, c = 0.0f;
  #pragma unroll
  for (int k = 0; k < NSPLIT; ++k) {
    float mk = pm[k * MB + i], sk = ps[k * MB + i], ck = pc[k * MB + i];
    float mn = fmaxf(m, mk);
    s = s * __expf(m - mn) + sk * __expf(mk - mn);
    m = mn; c += ck;
  }
  const float p = pos[i];
  // log S_i = m + log(s) + log(1-q_i) - log(n_miss)
  const float z = m + logf(s) + logf(1.0f - q[i]) - logf(c);
  const float hi = fmaxf(p, z), lo = fminf(p, z);
  float loss = -p + hi + log1pf(__expf(lo - hi));

  // reduce 256 threads -> 1 atomic
  #pragma unroll
  for (int off = 32; off; off >>= 1) loss += __shfl_down(loss, off, 64);
  __shared__ float red[4];
  if ((threadIdx.x & 63) == 0) red[threadIdx.x >> 6] = loss;
  __syncthreads();
  if (threadIdx.x == 0) {
    float t = red[0] + red[1] + red[2] + red[3];
    atomicAdd(out, t * (1.0f / (float)MB));
  }
}

extern "C" void kernel_launch(void* const* d_in, const int* in_sizes, int n_in,
                              void* d_out, int out_size, void* d_ws, size_t ws_size,
                              hipStream_t stream) {
  (void)in_sizes; (void)n_in; (void)out_size; (void)ws_size;
  const float* input_emb  = (const float*)d_in[0];
  const float* target_emb = (const float*)d_in[1];
  const int*   target_ids = (const int*)d_in[2];
  const float* q_probas   = (const float*)d_in[3];
  float* out = (float*)d_out;

  char* ws = (char*)d_ws;
  unsigned short* Abf = (unsigned short*)(ws);                    // 4 MB
  unsigned short* Bbf = (unsigned short*)(ws + 4194304);          // 4 MB
  float* logq = (float*)(ws + 8388608);                           // 32 KB
  float* pos  = (float*)(ws + 8421376);                           // 32 KB
  float* pm   = (float*)(ws + 8454144);                           // 256 KB
  float* psum = (float*)(ws + 8716288);                           // 256 KB
  float* pcnt = (float*)(ws + 8978432);                           // 256 KB

  hipMemsetAsync(out, 0, sizeof(float), stream);

  convert_kernel<<<2048, 256, 0, stream>>>(input_emb, target_emb, q_probas,
                                           Abf, Bbf, logq);
  possim_kernel<<<2048, 256, 0, stream>>>(input_emb, target_emb, pos);
  fused_kernel<<<dim3(MB / BM, NSPLIT), 256, 0, stream>>>(
      Abf, Bbf, target_ids, logq, pm, psum, pcnt);
  finalize_kernel<<<32, 256, 0, stream>>>(pm, psum, pcnt, pos, q_probas, out);
}

// Round 2
// 130.364 us; speedup vs baseline: 1.1461x; 1.1461x over previous
//
#include <hip/hip_runtime.h>
#include <hip/hip_bf16.h>
#include <stdint.h>

// Problem constants
#define MB 8192     // batch (rows and cols of sim)
#define KD 256      // embedding dim
#define BM 128      // rows per block (4 waves x 32 rows)
#define BN 64       // cols per chunk
#define NSPLIT 8    // column slabs
#define SLAB (MB / NSPLIT)   // 1024 cols per slab
#define VOCAB 1000000
#define COFF 104.0f          // fixed exp offset (see analysis: overflow/underflow-safe)

typedef __attribute__((ext_vector_type(8))) short bf16x8;
typedef __attribute__((ext_vector_type(4))) float f32x4;

__device__ __forceinline__ unsigned short f2bf(float x) {
  union { float f; uint32_t u; } v; v.f = x;
  uint32_t r = v.u + 0x7fffu + ((v.u >> 16) & 1u);   // RNE
  return (unsigned short)(r >> 16);
}

__device__ __forceinline__ float fast_exp(float x) {
#if __has_builtin(__builtin_amdgcn_exp2f)
  return __builtin_amdgcn_exp2f(x * 1.44269504088896340736f);
#else
  return __expf(x);
#endif
}

// ---- convert fp32->bf16 for A,B + pos_sim (fp32, wave per row) + zero hist ----
__global__ __launch_bounds__(256) void convertpos_kernel(
    const float* __restrict__ A, const float* __restrict__ B,
    unsigned short* __restrict__ Abf, unsigned short* __restrict__ Bbf,
    float* __restrict__ pos, int* __restrict__ hist) {
  int t = blockIdx.x * 256 + threadIdx.x;        // 524288 threads, 1 float4 each
  const float4 a = ((const float4*)A)[t];
  const float4 b = ((const float4*)B)[t];
  ushort4 oa, ob;
  oa.x = f2bf(a.x); oa.y = f2bf(a.y); oa.z = f2bf(a.z); oa.w = f2bf(a.w);
  ob.x = f2bf(b.x); ob.y = f2bf(b.y); ob.z = f2bf(b.z); ob.w = f2bf(b.w);
  ((ushort4*)Abf)[t] = oa;
  ((ushort4*)Bbf)[t] = ob;
  // pos_sim: wave (t>>6) == row, 64 lanes cover KD/4 float4 chunks
  float d = a.x * b.x + a.y * b.y + a.z * b.z + a.w * b.w;
  #pragma unroll
  for (int off = 32; off; off >>= 1) d += __shfl_down(d, off, 64);
  if ((threadIdx.x & 63) == 0) pos[t >> 6] = d;
  // zero the vocab histogram (1M ints == 524288 uint2)
  ((uint2*)hist)[t] = make_uint2(0u, 0u);
}

// ---- histogram of ids + b2 = -(log q + C) + zero accumulators ----
__global__ __launch_bounds__(256) void histb2_kernel(
    const int* __restrict__ ids, const float* __restrict__ q,
    int* __restrict__ hist, float* __restrict__ b2,
    float* __restrict__ ps, float* __restrict__ out) {
  int i = blockIdx.x * 256 + threadIdx.x;   // 32 blocks -> 8192 threads
  atomicAdd(&hist[ids[i]], 1);
  b2[i] = -(logf(q[i]) + COFF);
  ps[i] = 0.0f;
  if (i == 0) out[0] = 0.0f;
}

// ---- fused GEMM + masked fixed-offset exp-sum ----
__global__ __launch_bounds__(256, 3) void fused_kernel(
    const unsigned short* __restrict__ Abf,
    const unsigned short* __restrict__ Bbf,
    const int* __restrict__ ids,
    const float* __restrict__ b2,
    float* __restrict__ ps) {
  const int slab = blockIdx.y;
  const int tid = threadIdx.x;
  const int wave = tid >> 6;
  const int lane = tid & 63;
  const int quad = lane >> 4;
  const int lpos = lane & 15;
  const int rowbase = blockIdx.x * BM + wave * 32;

  // Fragment-ordered B staging: cell c = ((ct*8+kb)*4+quad)*16+lpos holds
  // B[col = ct*16+lpos][k = kb*32+quad*8 .. +8). Frag reads are wave-linear
  // (lane i -> byte 16*i) => conflict-free ds_read_b128.
  __shared__ unsigned short Bs[2048 * 8];    // 32 KB

  // A fragments resident: wave owns rows [rowbase, rowbase+32)
  bf16x8 afrag[2][8];
  #pragma unroll
  for (int rt = 0; rt < 2; ++rt)
    #pragma unroll
    for (int kb = 0; kb < 8; ++kb)
      afrag[rt][kb] = *(const bf16x8*)(Abf + (rowbase + rt * 16 + lpos) * KD + kb * 32 + quad * 8);

  int idr[2][4];
  float srun[2][4];
  #pragma unroll
  for (int rt = 0; rt < 2; ++rt)
    #pragma unroll
    for (int r = 0; r < 4; ++r) {
      idr[rt][r] = ids[rowbase + rt * 16 + quad * 4 + r];
      srun[rt][r] = 0.0f;
    }

  for (int ch = 0; ch < SLAB / BN; ++ch) {
    const int colchunk = slab * SLAB + ch * BN;
    __syncthreads();                         // protect Bs from overwrite
    #pragma unroll
    for (int s8 = 0; s8 < 8; ++s8) {
      int c = tid + s8 * 256;
      int lp = c & 15, qd = (c >> 4) & 3, kb = (c >> 6) & 7, ct = c >> 9;
      uint4 v = *(const uint4*)(Bbf + (colchunk + ct * 16 + lp) * KD + kb * 32 + qd * 8);
      *(uint4*)(Bs + c * 8) = v;             // linear in c: conflict-free
    }
    __syncthreads();

    #pragma unroll
    for (int ct = 0; ct < 4; ++ct) {
      const unsigned short* bp = Bs + (ct * 512 + quad * 16 + lpos) * 8;
      bf16x8 bfrag[8];
      #pragma unroll
      for (int kb = 0; kb < 8; ++kb)
        bfrag[kb] = *(const bf16x8*)(bp + kb * 512);
      const int j = colchunk + ct * 16 + lpos;
      const int idj = ids[j];
      const float bj = b2[j];
      #pragma unroll
      for (int rt = 0; rt < 2; ++rt) {
        f32x4 acc = {0.0f, 0.0f, 0.0f, 0.0f};
        #pragma unroll
        for (int kb = 0; kb < 8; ++kb)
          acc = __builtin_amdgcn_mfma_f32_16x16x32_bf16(afrag[rt][kb], bfrag[kb], acc, 0, 0, 0);
        // lane holds sim[rt*16 + quad*4 + r][ct*16 + lpos]
        #pragma unroll
        for (int r = 0; r < 4; ++r) {
          const float e = fast_exp(acc[r] + bj);   // exp(sim - log q_j - C)
          srun[rt][r] += (idj != idr[rt][r]) ? e : 0.0f;
        }
      }
    }
  }

  // sum across the 16 lanes of each quad (the 16 columns of the frag)
  #pragma unroll
  for (int rt = 0; rt < 2; ++rt)
    #pragma unroll
    for (int r = 0; r < 4; ++r) {
      float v = srun[rt][r];
      #pragma unroll
      for (int off = 1; off < 16; off <<= 1) v += __shfl_xor(v, off, 64);
      if (lpos == 0)
        atomicAdd(&ps[rowbase + rt * 16 + quad * 4 + r], v);
    }
}

// ---- finalize: per-row loss, mean ----
__global__ __launch_bounds__(256) void finalize_kernel(
    const float* __restrict__ ps, const float* __restrict__ pos,
    const float* __restrict__ q, const int* __restrict__ ids,
    const int* __restrict__ hist, float* __restrict__ out) {
  int i = blockIdx.x * 256 + threadIdx.x;   // 32 blocks -> 8192 threads
  const float s = ps[i];
  const float nm = (float)(MB - hist[ids[i]]);
  // log S_i = log(s) + C + log(1-q_i) - log(n_miss)
  const float z = logf(s) + COFF + logf(1.0f - q[i]) - logf(nm);
  const float p = pos[i];
  const float hi = fmaxf(p, z), lo = fminf(p, z);
  float loss = -p + hi + log1pf(__expf(lo - hi));

  #pragma unroll
  for (int off = 32; off; off >>= 1) loss += __shfl_down(loss, off, 64);
  __shared__ float red[4];
  if ((threadIdx.x & 63) == 0) red[threadIdx.x >> 6] = loss;
  __syncthreads();
  if (threadIdx.x == 0) {
    float t = red[0] + red[1] + red[2] + red[3];
    atomicAdd(out, t * (1.0f / (float)MB));
  }
}

extern "C" void kernel_launch(void* const* d_in, const int* in_sizes, int n_in,
                              void* d_out, int out_size, void* d_ws, size_t ws_size,
                              hipStream_t stream) {
  (void)in_sizes; (void)n_in; (void)out_size; (void)ws_size;
  const float* input_emb  = (const float*)d_in[0];
  const float* target_emb = (const float*)d_in[1];
  const int*   target_ids = (const int*)d_in[2];
  const float* q_probas   = (const float*)d_in[3];
  float* out = (float*)d_out;

  char* ws = (char*)d_ws;
  unsigned short* Abf = (unsigned short*)(ws);                    // 4 MB
  unsigned short* Bbf = (unsigned short*)(ws + (4u << 20));       // 4 MB
  int*   hist = (int*)  (ws + (8u << 20));                        // 4 MB
  float* b2   = (float*)(ws + (12u << 20));                       // 32 KB
  float* pos  = (float*)(ws + (12u << 20) + 32768);               // 32 KB
  float* ps   = (float*)(ws + (12u << 20) + 65536);               // 32 KB

  convertpos_kernel<<<2048, 256, 0, stream>>>(input_emb, target_emb, Abf, Bbf, pos, hist);
  histb2_kernel<<<32, 256, 0, stream>>>(target_ids, q_probas, hist, b2, ps, out);
  fused_kernel<<<dim3(MB / BM, NSPLIT), 256, 0, stream>>>(Abf, Bbf, target_ids, b2, ps);
  finalize_kernel<<<32, 256, 0, stream>>>(ps, pos, q_probas, target_ids, hist, out);
}